// Round 10
// baseline (524.439 us; speedup 1.0000x reference)
//
#include <hip/hip_runtime.h>
#include <hip/hip_cooperative_groups.h>
#include <math.h>

namespace cg = cooperative_groups;

#define NQ     16384
#define GW     128
#define GH     128

typedef __attribute__((ext_vector_type(8))) short short8;
typedef __attribute__((ext_vector_type(4))) float f32x4;

static __device__ __forceinline__ unsigned short f2bf(float f) {
    unsigned u = __builtin_bit_cast(unsigned, f);
    u += 0x7FFFu + ((u >> 16) & 1u);          // RNE
    return (unsigned short)(u >> 16);
}
static __device__ __forceinline__ unsigned pk2(float lo, float hi) {
    return (unsigned)f2bf(lo) | ((unsigned)f2bf(hi) << 16);
}
static __device__ __forceinline__ float bflo(unsigned u) {
    return __builtin_bit_cast(float, u << 16);
}
static __device__ __forceinline__ float bfhi(unsigned u) {
    return __builtin_bit_cast(float, u & 0xffff0000u);
}

// ---------------------------------------------------------------------------
// bf16 MFMA GEMM body — round-7 structure (measured best): tile 64x128,
// BK=64, 4 waves (2Mx2N), double-buffered LDS, single barrier per k-step,
// next-tile global loads issued before compute. 16B-chunk XOR bank swizzle.
// MODE 0: vproj  (A=fp32 A1, out bf16 ldc256, +bias)
// MODE 1: soaw   (A=concat(A1,A2) fp32, out fp32 ldc192 col<192, +bias)
// MODE 2: outproj(A=bf16 Abf,  out fp32 ldc256, +bias +resid)
// LDS: As 2x[64][64] bf16 (8KB each), Bs 2x[128][64] bf16 (16KB each) = 48KB
// ---------------------------------------------------------------------------
template<int KTOT, int MODE>
static __device__ __forceinline__ void gemm_body(
    int m0, int n0,
    const float* __restrict__ A1, const float* __restrict__ A2,
    const unsigned short* __restrict__ Abf,
    const unsigned short* __restrict__ WT,
    const float* __restrict__ bias, const float* __restrict__ resid,
    void* __restrict__ Cout,
    unsigned short* As, unsigned short* Bs)
{
    const int tid = threadIdx.x;
    const int w = tid >> 6, lane = tid & 63;
    const int wr = w >> 1, wc = w & 1;
    const int g = lane >> 4, r16 = lane & 15;
    const int arow = tid >> 3, aoc = tid & 7;   // staging coords
    const int NT = KTOT / 64;

    float4 ra[4];     // fp32 A staging: 2 rows x 2 float4
    uint4  rab[2];    // bf16 A staging
    uint4  rb[4];     // B staging: 4 rows x 1 uint4
    f32x4 acc[2][4] = {};

#define LOAD_T(t)                                                               \
    {                                                                           \
        int k0 = (t) * 64;                                                      \
        if (MODE == 2) {                                                        \
            _Pragma("unroll")                                                   \
            for (int i = 0; i < 2; ++i)                                         \
                rab[i] = *(const uint4*)&Abf[(size_t)(m0 + arow + i * 32) * 256 \
                                             + k0 + aoc * 8];                   \
        } else {                                                                \
            const float* Asrc = (KTOT == 512 && k0 >= 256) ? (A2 + (k0 - 256))  \
                                                           : (A1 + k0);         \
            _Pragma("unroll")                                                   \
            for (int i = 0; i < 2; ++i) {                                       \
                const float* p = Asrc + (size_t)(m0 + arow + i * 32) * 256      \
                                 + aoc * 8;                                     \
                ra[i * 2 + 0] = *(const float4*)p;                              \
                ra[i * 2 + 1] = *(const float4*)(p + 4);                        \
            }                                                                   \
        }                                                                       \
        _Pragma("unroll")                                                       \
        for (int i = 0; i < 4; ++i)                                             \
            rb[i] = *(const uint4*)&WT[(size_t)(n0 + arow + i * 32) * KTOT      \
                                       + k0 + aoc * 8];                         \
    }

#define SWZ(row, chunk) (((chunk) ^ ((row) & 7)) * 8)

#define WRITE_T(bufi)                                                           \
    {                                                                           \
        unsigned short* Ab = As + (bufi) * 64 * 64;                             \
        unsigned short* Bb = Bs + (bufi) * 128 * 64;                            \
        if (MODE == 2) {                                                        \
            _Pragma("unroll")                                                   \
            for (int i = 0; i < 2; ++i) {                                       \
                int r = arow + i * 32;                                          \
                *(uint4*)&Ab[r * 64 + SWZ(r, aoc)] = rab[i];                    \
            }                                                                   \
        } else {                                                                \
            _Pragma("unroll")                                                   \
            for (int i = 0; i < 2; ++i) {                                       \
                uint4 wv;                                                       \
                wv.x = pk2(ra[i * 2].x, ra[i * 2].y);                           \
                wv.y = pk2(ra[i * 2].z, ra[i * 2].w);                           \
                wv.z = pk2(ra[i * 2 + 1].x, ra[i * 2 + 1].y);                   \
                wv.w = pk2(ra[i * 2 + 1].z, ra[i * 2 + 1].w);                   \
                int r = arow + i * 32;                                          \
                *(uint4*)&Ab[r * 64 + SWZ(r, aoc)] = wv;                        \
            }                                                                   \
        }                                                                       \
        _Pragma("unroll")                                                       \
        for (int i = 0; i < 4; ++i) {                                           \
            int r = arow + i * 32;                                              \
            *(uint4*)&Bb[r * 64 + SWZ(r, aoc)] = rb[i];                         \
        }                                                                       \
    }

    LOAD_T(0);
    WRITE_T(0);
    __syncthreads();

    for (int t = 0; t < NT; ++t) {
        if (t + 1 < NT) LOAD_T(t + 1);       // issue next tile's global loads
        const unsigned short* Ab = As + (t & 1) * 64 * 64;
        const unsigned short* Bb = Bs + (t & 1) * 128 * 64;
        #pragma unroll
        for (int kh = 0; kh < 2; ++kh) {
            short8 af[2], bfr[4];
            #pragma unroll
            for (int mi = 0; mi < 2; ++mi) {
                int r = wr * 32 + mi * 16 + r16;
                af[mi] = *(const short8*)&Ab[r * 64 + SWZ(r, kh * 4 + g)];
            }
            #pragma unroll
            for (int nj = 0; nj < 4; ++nj) {
                int r = wc * 64 + nj * 16 + r16;
                bfr[nj] = *(const short8*)&Bb[r * 64 + SWZ(r, kh * 4 + g)];
            }
            #pragma unroll
            for (int mi = 0; mi < 2; ++mi)
                #pragma unroll
                for (int nj = 0; nj < 4; ++nj)
                    acc[mi][nj] = __builtin_amdgcn_mfma_f32_16x16x32_bf16(
                        af[mi], bfr[nj], acc[mi][nj], 0, 0, 0);
        }
        if (t + 1 < NT) WRITE_T((t + 1) & 1);  // lands in the other buffer
        __syncthreads();
    }
#undef LOAD_T
#undef WRITE_T
#undef SWZ

    #pragma unroll
    for (int mi = 0; mi < 2; ++mi) {
        int row = m0 + wr * 32 + mi * 16 + g * 4;
        #pragma unroll
        for (int nj = 0; nj < 4; ++nj) {
            int col = n0 + wc * 64 + nj * 16 + r16;
            if (MODE == 1 && col >= 192) continue;
            float bia = bias[col];
            #pragma unroll
            for (int j = 0; j < 4; ++j) {
                float vo = acc[mi][nj][j] + bia;
                if (MODE == 0) {
                    ((unsigned short*)Cout)[(size_t)(row + j) * 256 + col] = f2bf(vo);
                } else if (MODE == 1) {
                    ((float*)Cout)[(size_t)(row + j) * 192 + col] = vo;
                } else {
                    ((float*)Cout)[(size_t)(row + j) * 256 + col] =
                        vo + resid[(size_t)(row + j) * 256 + col];
                }
            }
        }
    }
}

// ---------------------------------------------------------------------------
// Sampler iteration (round-7 v4 body): 4 q per 256-thread pass, one wave per q.
// lane ln: b=ln>>5 (temporal half), h=(ln>>2)&7, c=ln&3; 16B gathers;
// halves combined via __shfl_xor(32). so_s/w_s/rp_s live in caller's LDS.
// ---------------------------------------------------------------------------
static __device__ __forceinline__ void acc8(float* acc, float w, uint4 r) {
    acc[0] = fmaf(w, bflo(r.x), acc[0]);
    acc[1] = fmaf(w, bfhi(r.x), acc[1]);
    acc[2] = fmaf(w, bflo(r.y), acc[2]);
    acc[3] = fmaf(w, bfhi(r.y), acc[3]);
    acc[4] = fmaf(w, bflo(r.z), acc[4]);
    acc[5] = fmaf(w, bfhi(r.z), acc[5]);
    acc[6] = fmaf(w, bflo(r.w), acc[6]);
    acc[7] = fmaf(w, bfhi(r.w), acc[7]);
}

static __device__ __forceinline__ void sampler_iter(
    int grp, const unsigned short* __restrict__ v, const float* __restrict__ soaw,
    const float* __restrict__ rp, unsigned short* __restrict__ outm,
    float* so_s /*[4][128]*/, float* w_s /*[4][64]*/, float* rp_s /*[4][2]*/)
{
    const int t = threadIdx.x;
    // XCD band swizzle (grp%8 == blockIdx%8 preserved by the +768 loop)
    const int q0 = ((grp & 7) * 512 + (grp >> 3)) * 4;

    #pragma unroll
    for (int i = 0; i < 2; ++i) {
        int idx = t + i * 256;
        int qq = idx >> 7, off = idx & 127;
        so_s[qq * 128 + off] = soaw[(size_t)(q0 + qq) * 192 + off];
    }
    if (t < 64) {             // in-lane softmax: one lane per (q, h, b)
        int qq = t >> 4, gi = t & 15;
        float4 a4 = *reinterpret_cast<const float4*>(
            &soaw[(size_t)(q0 + qq) * 192 + 128 + gi * 4]);
        float m = fmaxf(fmaxf(a4.x, a4.y), fmaxf(a4.z, a4.w));
        float e0 = __expf(a4.x - m), e1 = __expf(a4.y - m);
        float e2 = __expf(a4.z - m), e3 = __expf(a4.w - m);
        float inv = 1.f / (e0 + e1 + e2 + e3);
        w_s[qq * 64 + gi * 4 + 0] = e0 * inv;
        w_s[qq * 64 + gi * 4 + 1] = e1 * inv;
        w_s[qq * 64 + gi * 4 + 2] = e2 * inv;
        w_s[qq * 64 + gi * 4 + 3] = e3 * inv;
    }
    if (t < 8) rp_s[(t >> 1) * 2 + (t & 1)] = rp[(size_t)(q0 + (t >> 1)) * 2 + (t & 1)];
    __syncthreads();

    const int wq = t >> 6;
    const int q = q0 + wq;
    const int ln = t & 63;
    const int bb = ln >> 5;
    const int s = ln & 31;
    const int h = s >> 2, c = s & 3;
    const int sub = h * 64 + c * 16;
    const float rpx = rp_s[wq * 2], rpy = rp_s[wq * 2 + 1];
    const char* vb = (const char*)v + (size_t)bb * NQ * 512;
    float acc[8] = {};

    #pragma unroll
    for (int p = 0; p < 4; ++p) {
        float sox = so_s[wq * 128 + h * 16 + bb * 8 + p * 2 + 0];
        float soy = so_s[wq * 128 + h * 16 + bb * 8 + p * 2 + 1];
        float wbp = w_s[wq * 64 + h * 8 + bb * 4 + p];
        float px = (rpx + sox * (1.0f / 128.0f)) * 128.0f - 0.5f;
        float py = (rpy + soy * (1.0f / 128.0f)) * 128.0f - 0.5f;
        float x0f = floorf(px), y0f = floorf(py);
        float lx = px - x0f, ly = py - y0f;
        int x0 = (int)x0f, y0 = (int)y0f;
        int x1 = x0 + 1, y1 = y0 + 1;
        float wx0 = (1.f - lx) * ((x0 >= 0 && x0 < GW) ? 1.f : 0.f);
        float wx1 = lx         * ((x1 >= 0 && x1 < GW) ? 1.f : 0.f);
        float wy0 = (1.f - ly) * ((y0 >= 0 && y0 < GH) ? 1.f : 0.f);
        float wy1 = ly         * ((y1 >= 0 && y1 < GH) ? 1.f : 0.f);
        int x0c = min(max(x0, 0), GW - 1), x1c = min(max(x1, 0), GW - 1);
        int y0c = min(max(y0, 0), GH - 1), y1c = min(max(y1, 0), GH - 1);
        uint4 r00 = *(const uint4*)(vb + ((size_t)(y0c * GW + x0c) * 512 + sub));
        uint4 r10 = *(const uint4*)(vb + ((size_t)(y0c * GW + x1c) * 512 + sub));
        uint4 r01 = *(const uint4*)(vb + ((size_t)(y1c * GW + x0c) * 512 + sub));
        uint4 r11 = *(const uint4*)(vb + ((size_t)(y1c * GW + x1c) * 512 + sub));
        acc8(acc, wbp * wx0 * wy0, r00);
        acc8(acc, wbp * wx1 * wy0, r10);
        acc8(acc, wbp * wx0 * wy1, r01);
        acc8(acc, wbp * wx1 * wy1, r11);
    }

    #pragma unroll
    for (int i = 0; i < 8; ++i) acc[i] += __shfl_xor(acc[i], 32);

    if (bb == 0) {
        uint4 o;
        o.x = pk2(0.5f * acc[0], 0.5f * acc[1]);
        o.y = pk2(0.5f * acc[2], 0.5f * acc[3]);
        o.z = pk2(0.5f * acc[4], 0.5f * acc[5]);
        o.w = pk2(0.5f * acc[6], 0.5f * acc[7]);
        *reinterpret_cast<uint4*>((char*)outm + (size_t)q * 512 + sub) = o;
    }
    __syncthreads();   // so_s/w_s reused next iteration
}

// ---------------------------------------------------------------------------
// Fused cooperative kernel: 768 blocks x 256 threads, 48KB LDS -> exactly
// 3 blocks/CU co-resident. Phases split by grid.sync():
//   P0 weight prep | P1 vproj+soaw | P2 sampler | P3 outproj
// ---------------------------------------------------------------------------
__global__ __launch_bounds__(256, 3)
void fused(const float* __restrict__ query, const float* __restrict__ value,
           const float* __restrict__ rp,
           const float* __restrict__ Wv, const float* __restrict__ bv,
           const float* __restrict__ Wso, const float* __restrict__ bso,
           const float* __restrict__ Waw, const float* __restrict__ baw,
           const float* __restrict__ Wo, const float* __restrict__ bo,
           unsigned short* __restrict__ WTv, unsigned short* __restrict__ WTso,
           unsigned short* __restrict__ WTo, float* __restrict__ bias2,
           unsigned short* __restrict__ ws_v, float* __restrict__ ws_soaw,
           unsigned short* __restrict__ ws_mean, float* __restrict__ out)
{
    __shared__ __align__(16) unsigned short As[2 * 64 * 64];
    __shared__ __align__(16) unsigned short Bs[2 * 128 * 64];
    cg::grid_group gr = cg::this_grid();
    const int bid = blockIdx.x;
    const int t = threadIdx.x;

    // ---- P0: weight transpose+convert (768 blocks cover all 3 matrices) ----
    if (bid < 256) {
        WTv[bid * 256 + t] = f2bf(Wv[(size_t)t * 256 + bid]);
    } else if (bid < 512) {
        int n = bid - 256;
        WTo[n * 256 + t] = f2bf(Wo[(size_t)t * 256 + n]);
    } else {
        int n = bid - 512;
        float s0, s1;
        if (n < 128)      { s0 = Wso[(size_t)t * 128 + n];       s1 = Wso[(size_t)(t + 256) * 128 + n]; }
        else if (n < 192) { s0 = Waw[(size_t)t * 64 + n - 128];  s1 = Waw[(size_t)(t + 256) * 64 + n - 128]; }
        else              { s0 = 0.f; s1 = 0.f; }
        WTso[(size_t)n * 512 + t]       = f2bf(s0);
        WTso[(size_t)n * 512 + t + 256] = f2bf(s1);
        if (t == 0) bias2[n] = (n < 128) ? bso[n] : ((n < 192) ? baw[n - 128] : 0.f);
    }
    __threadfence();
    gr.sync();

    // ---- P1: vproj (1024 roles) + soaw (512 roles), balanced 2-3 units ----
    if (bid < 512) {
        gemm_body<256, 0>((bid >> 1) * 64, (bid & 1) * 128,
                          value, nullptr, nullptr, WTv, bv, nullptr, ws_v, As, Bs);
        __syncthreads();
        gemm_body<512, 1>((bid >> 1) * 64, (bid & 1) * 128,
                          value, query, nullptr, WTso, bias2, nullptr, ws_soaw, As, Bs);
    } else {
        int r0 = 512 + 2 * (bid - 512);
        gemm_body<256, 0>((r0 >> 1) * 64, (r0 & 1) * 128,
                          value, nullptr, nullptr, WTv, bv, nullptr, ws_v, As, Bs);
        __syncthreads();
        int r1 = r0 + 1;
        gemm_body<256, 0>((r1 >> 1) * 64, (r1 & 1) * 128,
                          value, nullptr, nullptr, WTv, bv, nullptr, ws_v, As, Bs);
    }
    __threadfence();
    gr.sync();

    // ---- P2: sampler, 4096 4-q groups over 768 blocks (XCD band kept) ----
    {
        float* so_s = (float*)As;            // 4*128 floats = 2KB
        float* w_s  = (float*)As + 512;      // 4*64 = 1KB
        float* rp_s = (float*)As + 768;      // 8 floats
        for (int grp = bid; grp < 4096; grp += 768)
            sampler_iter(grp, ws_v, ws_soaw, rp, ws_mean, so_s, w_s, rp_s);
    }
    __threadfence();
    gr.sync();

    // ---- P3: outproj (512 roles; blocks 512+ idle) ----
    if (bid < 512) {
        gemm_body<256, 2>((bid >> 1) * 64, (bid & 1) * 128,
                          nullptr, nullptr, ws_mean, WTo, bo, query, out, As, Bs);
    }
}

// ---------------------------------------------------------------------------
// Fallback path (round-7 4-kernel pipeline) if cooperative launch fails.
// ---------------------------------------------------------------------------
__global__ void prep_k(const float* __restrict__ Wv, const float* __restrict__ Wso,
                       const float* __restrict__ Waw, const float* __restrict__ bso,
                       const float* __restrict__ baw, const float* __restrict__ Wo,
                       unsigned short* __restrict__ WTv, unsigned short* __restrict__ WTso,
                       unsigned short* __restrict__ WTo, float* __restrict__ bias2)
{
    const int n = blockIdx.x, k = threadIdx.x;
    WTv[n * 256 + k] = f2bf(Wv[(size_t)k * 256 + n]);
    WTo[n * 256 + k] = f2bf(Wo[(size_t)k * 256 + n]);
    float s0, s1;
    if (n < 128)      { s0 = Wso[(size_t)k * 128 + n];       s1 = Wso[(size_t)(k + 256) * 128 + n]; }
    else if (n < 192) { s0 = Waw[(size_t)k * 64 + n - 128];  s1 = Waw[(size_t)(k + 256) * 64 + n - 128]; }
    else              { s0 = 0.f; s1 = 0.f; }
    WTso[(size_t)n * 512 + k]       = f2bf(s0);
    WTso[(size_t)n * 512 + k + 256] = f2bf(s1);
    if (k == 0) bias2[n] = (n < 128) ? bso[n] : ((n < 192) ? baw[n - 128] : 0.f);
}

__global__ __launch_bounds__(256)
void gemm_vs_k(const float* __restrict__ value, const float* __restrict__ query,
               const unsigned short* __restrict__ WTv, const unsigned short* __restrict__ WTso,
               const float* __restrict__ bv, const float* __restrict__ bias2,
               unsigned short* __restrict__ v_out, float* __restrict__ soaw_out)
{
    __shared__ __align__(16) unsigned short As[2 * 64 * 64];
    __shared__ __align__(16) unsigned short Bs[2 * 128 * 64];
    const int bid = blockIdx.x;
    if (bid < 1024) {
        gemm_body<256, 0>((bid >> 1) * 64, (bid & 1) * 128,
                          value, nullptr, nullptr, WTv, bv, nullptr, v_out, As, Bs);
    } else {
        const int b2 = bid - 1024;
        gemm_body<512, 1>((b2 >> 1) * 64, (b2 & 1) * 128,
                          value, query, nullptr, WTso, bias2, nullptr, soaw_out, As, Bs);
    }
}

__global__ __launch_bounds__(256)
void sampler_k(const unsigned short* __restrict__ v, const float* __restrict__ soaw,
               const float* __restrict__ rp, unsigned short* __restrict__ outm)
{
    __shared__ float so_s[4 * 128];
    __shared__ float w_s[4 * 64];
    __shared__ float rp_s[8];
    sampler_iter(blockIdx.x, v, soaw, rp, outm, so_s, w_s, rp_s);
}

__global__ __launch_bounds__(256)
void gemm_out_k(const unsigned short* __restrict__ Abf, const unsigned short* __restrict__ WTo,
                const float* __restrict__ bo, const float* __restrict__ resid,
                float* __restrict__ out)
{
    __shared__ __align__(16) unsigned short As[2 * 64 * 64];
    __shared__ __align__(16) unsigned short Bs[2 * 128 * 64];
    gemm_body<256, 2>((blockIdx.x >> 1) * 64, (blockIdx.x & 1) * 128,
                      nullptr, nullptr, Abf, WTo, bo, resid, out, As, Bs);
}

// ---------------------------------------------------------------------------
extern "C" void kernel_launch(void* const* d_in, const int* in_sizes, int n_in,
                              void* d_out, int out_size, void* d_ws, size_t ws_size,
                              hipStream_t stream)
{
    const float* query   = (const float*)d_in[0];
    const float* value   = (const float*)d_in[1];
    const float* rp      = (const float*)d_in[2];
    const float* W_vproj = (const float*)d_in[3];
    const float* b_vproj = (const float*)d_in[4];
    const float* W_so    = (const float*)d_in[5];
    const float* b_so    = (const float*)d_in[6];
    const float* W_aw    = (const float*)d_in[7];
    const float* b_aw    = (const float*)d_in[8];
    const float* W_out   = (const float*)d_in[9];
    const float* b_out   = (const float*)d_in[10];
    float* out = (float*)d_out;

    char* wp = (char*)d_ws;
    unsigned short* ws_v    = (unsigned short*)wp; wp += (size_t)2 * NQ * 256 * 2;
    float*          ws_soaw = (float*)wp;          wp += (size_t)NQ * 192 * 4;
    unsigned short* ws_mean = (unsigned short*)wp; wp += (size_t)NQ * 256 * 2;
    unsigned short* WTv     = (unsigned short*)wp; wp += 256 * 256 * 2;
    unsigned short* WTso    = (unsigned short*)wp; wp += 256 * 512 * 2;
    unsigned short* WTo     = (unsigned short*)wp; wp += 256 * 256 * 2;
    float*          bias2   = (float*)wp;          wp += 256 * 4;

    void* args[] = {
        (void*)&query, (void*)&value, (void*)&rp,
        (void*)&W_vproj, (void*)&b_vproj, (void*)&W_so, (void*)&b_so,
        (void*)&W_aw, (void*)&b_aw, (void*)&W_out, (void*)&b_out,
        (void*)&WTv, (void*)&WTso, (void*)&WTo, (void*)&bias2,
        (void*)&ws_v, (void*)&ws_soaw, (void*)&ws_mean, (void*)&out
    };
    hipError_t err = hipLaunchCooperativeKernel(
        (const void*)fused, dim3(768), dim3(256), args, 0, stream);

    if (err != hipSuccess) {
        // fallback: round-7 4-kernel pipeline
        prep_k<<<dim3(256), dim3(256), 0, stream>>>(W_vproj, W_so, W_aw, b_so, b_aw,
                                                    W_out, WTv, WTso, WTo, bias2);
        gemm_vs_k<<<dim3(1536), dim3(256), 0, stream>>>(value, query, WTv, WTso,
                                                        b_vproj, bias2, ws_v, ws_soaw);
        sampler_k<<<dim3(4096), dim3(256), 0, stream>>>(ws_v, ws_soaw, rp, ws_mean);
        gemm_out_k<<<dim3(512), dim3(256), 0, stream>>>(ws_mean, WTo, b_out, query, out);
    }
}

// Round 11
// 89.999 us; speedup vs baseline: 5.8271x; 5.8271x over previous
//
#include <hip/hip_runtime.h>
#include <math.h>

#define NQ     16384
#define GW     128
#define GH     128

typedef __attribute__((ext_vector_type(8))) short short8;
typedef __attribute__((ext_vector_type(4))) float f32x4;

static __device__ __forceinline__ unsigned short f2bf(float f) {
    unsigned u = __builtin_bit_cast(unsigned, f);
    u += 0x7FFFu + ((u >> 16) & 1u);          // RNE
    return (unsigned short)(u >> 16);
}
static __device__ __forceinline__ unsigned pk2(float lo, float hi) {
    return (unsigned)f2bf(lo) | ((unsigned)f2bf(hi) << 16);
}
static __device__ __forceinline__ float bflo(unsigned u) {
    return __builtin_bit_cast(float, u << 16);
}
static __device__ __forceinline__ float bfhi(unsigned u) {
    return __builtin_bit_cast(float, u & 0xffff0000u);
}

// ---------------------------------------------------------------------------
// prep: bf16 transposed weights  WT[n][k] = W[k][n]  (+ padded soaw weights)
// ---------------------------------------------------------------------------
__global__ void prep(const float* __restrict__ Wv, const float* __restrict__ Wso,
                     const float* __restrict__ Waw, const float* __restrict__ bso,
                     const float* __restrict__ baw, const float* __restrict__ Wo,
                     unsigned short* __restrict__ WTv, unsigned short* __restrict__ WTso,
                     unsigned short* __restrict__ WTo, float* __restrict__ bias2)
{
    const int n = blockIdx.x;     // 0..255
    const int k = threadIdx.x;    // 0..255
    WTv[n * 256 + k] = f2bf(Wv[(size_t)k * 256 + n]);
    WTo[n * 256 + k] = f2bf(Wo[(size_t)k * 256 + n]);
    float s0, s1;
    if (n < 128)      { s0 = Wso[(size_t)k * 128 + n];       s1 = Wso[(size_t)(k + 256) * 128 + n]; }
    else if (n < 192) { s0 = Waw[(size_t)k * 64 + n - 128];  s1 = Waw[(size_t)(k + 256) * 64 + n - 128]; }
    else              { s0 = 0.f; s1 = 0.f; }
    WTso[(size_t)n * 512 + k]       = f2bf(s0);
    WTso[(size_t)n * 512 + k + 256] = f2bf(s1);
    if (k == 0) bias2[n] = (n < 128) ? bso[n] : ((n < 192) ? baw[n - 128] : 0.f);
}

// ---------------------------------------------------------------------------
// bf16 MFMA GEMM body, tile 64(M)x128(N), BK=32, 4 waves (2Mx2N), wave=32x64.
// Double-buffered LDS (24 KB total -> 6 blocks/CU, 24 waves = the latency-
// hiding that BK=64/48KB/3-blocks lacked). Single barrier per k-step, next
// tile's loads issued before compute (1 step lookahead).
// LDS rows are 64B (32 bf16, 4x16B chunks). Bank base = 16*(row&1), so the
// swizzle chunk ^= (row>>1)&3 spreads same-parity rows across chunk slots:
// 2-way (free) on both ds_write_b128 and ds_read_b128.
// MODE 0: vproj  (A=fp32 A1, out bf16 ldc256, +bias)
// MODE 1: soaw   (A=concat(A1,A2) fp32, out fp32 ldc192 col<192, +bias)
// MODE 2: outproj(A=bf16 Abf,  out fp32 ldc256, +bias +resid)
// ---------------------------------------------------------------------------
#define SWZ(row, chunk) ((((chunk) ^ (((row) >> 1) & 3))) * 8)

template<int KTOT, int MODE>
static __device__ __forceinline__ void gemm_body(
    int m0, int n0,
    const float* __restrict__ A1, const float* __restrict__ A2,
    const unsigned short* __restrict__ Abf,
    const unsigned short* __restrict__ WT,
    const float* __restrict__ bias, const float* __restrict__ resid,
    void* __restrict__ Cout,
    unsigned short* As, unsigned short* Bs)
{
    const int tid = threadIdx.x;
    const int w = tid >> 6, lane = tid & 63;
    const int wr = w >> 1, wc = w & 1;
    const int g = lane >> 4, r16 = lane & 15;
    const int arow = tid >> 2, aoc = tid & 3;   // A staging: row 0..63, chunk 0..3
    const int NT = KTOT / 32;

    float4 ra[2];     // fp32 A staging: one row-chunk (8 floats)
    uint4  rab;       // bf16 A staging
    uint4  rb[2];     // B staging: 2 chunks
    f32x4 acc[2][4] = {};

#define LOAD_T(t)                                                               \
    {                                                                           \
        int k0 = (t) * 32;                                                      \
        if (MODE == 2) {                                                        \
            rab = *(const uint4*)&Abf[(size_t)(m0 + arow) * 256 + k0 + aoc * 8];\
        } else {                                                                \
            const float* Asrc = (KTOT == 512 && k0 >= 256) ? (A2 + (k0 - 256))  \
                                                           : (A1 + k0);         \
            const float* p = Asrc + (size_t)(m0 + arow) * 256 + aoc * 8;        \
            ra[0] = *(const float4*)p;                                          \
            ra[1] = *(const float4*)(p + 4);                                    \
        }                                                                       \
        _Pragma("unroll")                                                       \
        for (int j = 0; j < 2; ++j) {                                           \
            int id = tid + j * 256;                                             \
            int r = id >> 2, c = id & 3;                                        \
            rb[j] = *(const uint4*)&WT[(size_t)(n0 + r) * KTOT + k0 + c * 8];   \
        }                                                                       \
    }

#define WRITE_T(bufi)                                                           \
    {                                                                           \
        unsigned short* Ab = As + (bufi) * 64 * 32;                             \
        unsigned short* Bb = Bs + (bufi) * 128 * 32;                            \
        if (MODE == 2) {                                                        \
            *(uint4*)&Ab[arow * 32 + SWZ(arow, aoc)] = rab;                     \
        } else {                                                                \
            uint4 wv;                                                           \
            wv.x = pk2(ra[0].x, ra[0].y); wv.y = pk2(ra[0].z, ra[0].w);         \
            wv.z = pk2(ra[1].x, ra[1].y); wv.w = pk2(ra[1].z, ra[1].w);         \
            *(uint4*)&Ab[arow * 32 + SWZ(arow, aoc)] = wv;                      \
        }                                                                       \
        _Pragma("unroll")                                                       \
        for (int j = 0; j < 2; ++j) {                                           \
            int id = tid + j * 256;                                             \
            int r = id >> 2, c = id & 3;                                        \
            *(uint4*)&Bb[r * 32 + SWZ(r, c)] = rb[j];                           \
        }                                                                       \
    }

    LOAD_T(0);
    WRITE_T(0);
    __syncthreads();

    for (int t = 0; t < NT; ++t) {
        if (t + 1 < NT) LOAD_T(t + 1);       // issue next tile's global loads
        const unsigned short* Ab = As + (t & 1) * 64 * 32;
        const unsigned short* Bb = Bs + (t & 1) * 128 * 32;
        short8 af[2], bfr[4];
        #pragma unroll
        for (int mi = 0; mi < 2; ++mi) {
            int r = wr * 32 + mi * 16 + r16;
            af[mi] = *(const short8*)&Ab[r * 32 + SWZ(r, g)];
        }
        #pragma unroll
        for (int nj = 0; nj < 4; ++nj) {
            int r = wc * 64 + nj * 16 + r16;
            bfr[nj] = *(const short8*)&Bb[r * 32 + SWZ(r, g)];
        }
        #pragma unroll
        for (int mi = 0; mi < 2; ++mi)
            #pragma unroll
            for (int nj = 0; nj < 4; ++nj)
                acc[mi][nj] = __builtin_amdgcn_mfma_f32_16x16x32_bf16(
                    af[mi], bfr[nj], acc[mi][nj], 0, 0, 0);
        if (t + 1 < NT) WRITE_T((t + 1) & 1);  // lands in the other buffer
        __syncthreads();
    }
#undef LOAD_T
#undef WRITE_T

    #pragma unroll
    for (int mi = 0; mi < 2; ++mi) {
        int row = m0 + wr * 32 + mi * 16 + g * 4;
        #pragma unroll
        for (int nj = 0; nj < 4; ++nj) {
            int col = n0 + wc * 64 + nj * 16 + r16;
            if (MODE == 1 && col >= 192) continue;
            float bia = bias[col];
            #pragma unroll
            for (int j = 0; j < 4; ++j) {
                float vo = acc[mi][nj][j] + bia;
                if (MODE == 0) {
                    ((unsigned short*)Cout)[(size_t)(row + j) * 256 + col] = f2bf(vo);
                } else if (MODE == 1) {
                    ((float*)Cout)[(size_t)(row + j) * 192 + col] = vo;
                } else {
                    ((float*)Cout)[(size_t)(row + j) * 256 + col] =
                        vo + resid[(size_t)(row + j) * 256 + col];
                }
            }
        }
    }
}

// ---------------------------------------------------------------------------
// Pair swizzle: blocks b and b+8 (same XCD, since XCD = b%8) are the two
// n-tiles of one m-tile -> shared A-tile HBM-fetched once per XCD.
// ---------------------------------------------------------------------------
__global__ __launch_bounds__(256, 5)
void gemm_vs(const float* __restrict__ value, const float* __restrict__ query,
             const unsigned short* __restrict__ WTv, const unsigned short* __restrict__ WTso,
             const float* __restrict__ bv, const float* __restrict__ bias2,
             unsigned short* __restrict__ v_out, float* __restrict__ soaw_out)
{
    __shared__ __align__(16) unsigned short As[2 * 64 * 32];
    __shared__ __align__(16) unsigned short Bs[2 * 128 * 32];
    const int bid = blockIdx.x;
    if (bid < 1024) {
        const int role = ((bid >> 4) * 8 + (bid & 7)) * 2 + ((bid >> 3) & 1);
        gemm_body<256, 0>((role >> 1) * 64, (role & 1) * 128,
                          value, nullptr, nullptr, WTv, bv, nullptr, v_out, As, Bs);
    } else {
        const int j = bid - 1024;
        const int role = ((j >> 4) * 8 + (j & 7)) * 2 + ((j >> 3) & 1);
        gemm_body<512, 1>((role >> 1) * 64, (role & 1) * 128,
                          value, query, nullptr, WTso, bias2, nullptr, soaw_out, As, Bs);
    }
}

__global__ __launch_bounds__(256, 5)
void gemm_out(const unsigned short* __restrict__ Abf, const unsigned short* __restrict__ WTo,
              const float* __restrict__ bo, const float* __restrict__ resid,
              float* __restrict__ out)
{
    __shared__ __align__(16) unsigned short As[2 * 64 * 32];
    __shared__ __align__(16) unsigned short Bs[2 * 128 * 32];
    const int b = blockIdx.x;
    const int role = ((b >> 4) * 8 + (b & 7)) * 2 + ((b >> 3) & 1);
    gemm_body<256, 2>((role >> 1) * 64, (role & 1) * 128,
                      nullptr, nullptr, Abf, WTo, bo, resid, out, As, Bs);
}

// ---------------------------------------------------------------------------
// Sampler v4 (round-7, unchanged): one WAVE per q. lane ln: b=ln>>5,
// h=(ln>>2)&7, c=ln&3. 16 uint4 gathers/lane; halves via __shfl_xor(32).
// 4096 blocks (4 q each), XCD-aware band swizzle (band fits 4MB L2).
// ---------------------------------------------------------------------------
static __device__ __forceinline__ void acc8(float* acc, float w, uint4 r) {
    acc[0] = fmaf(w, bflo(r.x), acc[0]);
    acc[1] = fmaf(w, bfhi(r.x), acc[1]);
    acc[2] = fmaf(w, bflo(r.y), acc[2]);
    acc[3] = fmaf(w, bfhi(r.y), acc[3]);
    acc[4] = fmaf(w, bflo(r.z), acc[4]);
    acc[5] = fmaf(w, bfhi(r.z), acc[5]);
    acc[6] = fmaf(w, bflo(r.w), acc[6]);
    acc[7] = fmaf(w, bfhi(r.w), acc[7]);
}

__global__ __launch_bounds__(256)
void sampler(const unsigned short* __restrict__ v, const float* __restrict__ soaw,
             const float* __restrict__ rp, unsigned short* __restrict__ outm)
{
    __shared__ float so_s[4][128];
    __shared__ float w_s[4][64];
    __shared__ float rp_s[4][2];

    const int t = threadIdx.x;
    const int bid = blockIdx.x;
    const int q0 = ((bid & 7) * 512 + (bid >> 3)) * 4;

    #pragma unroll
    for (int i = 0; i < 2; ++i) {
        int idx = t + i * 256;
        int qq = idx >> 7, off = idx & 127;
        so_s[qq][off] = soaw[(size_t)(q0 + qq) * 192 + off];
    }
    if (t < 64) {             // in-lane softmax: one lane per (q, h, b)
        int qq = t >> 4, grp = t & 15;
        float4 a4 = *reinterpret_cast<const float4*>(
            &soaw[(size_t)(q0 + qq) * 192 + 128 + grp * 4]);
        float m = fmaxf(fmaxf(a4.x, a4.y), fmaxf(a4.z, a4.w));
        float e0 = __expf(a4.x - m), e1 = __expf(a4.y - m);
        float e2 = __expf(a4.z - m), e3 = __expf(a4.w - m);
        float inv = 1.f / (e0 + e1 + e2 + e3);
        w_s[qq][grp * 4 + 0] = e0 * inv;
        w_s[qq][grp * 4 + 1] = e1 * inv;
        w_s[qq][grp * 4 + 2] = e2 * inv;
        w_s[qq][grp * 4 + 3] = e3 * inv;
    }
    if (t < 8) rp_s[t >> 1][t & 1] = rp[(size_t)(q0 + (t >> 1)) * 2 + (t & 1)];
    __syncthreads();

    const int wq = t >> 6;                 // block-local q (0..3), one wave each
    const int q = q0 + wq;
    const int ln = t & 63;
    const int b = ln >> 5;                 // temporal half on lanes
    const int s = ln & 31;
    const int h = s >> 2, c = s & 3;
    const int sub = h * 64 + c * 16;       // byte offset inside a 512B v row
    const float rpx = rp_s[wq][0], rpy = rp_s[wq][1];
    const char* vb = (const char*)v + (size_t)b * NQ * 512;
    float acc[8] = {};

    #pragma unroll
    for (int p = 0; p < 4; ++p) {
        float sox = so_s[wq][h * 16 + b * 8 + p * 2 + 0];
        float soy = so_s[wq][h * 16 + b * 8 + p * 2 + 1];
        float wbp = w_s[wq][h * 8 + b * 4 + p];
        float px = (rpx + sox * (1.0f / 128.0f)) * 128.0f - 0.5f;
        float py = (rpy + soy * (1.0f / 128.0f)) * 128.0f - 0.5f;
        float x0f = floorf(px), y0f = floorf(py);
        float lx = px - x0f, ly = py - y0f;
        int x0 = (int)x0f, y0 = (int)y0f;
        int x1 = x0 + 1, y1 = y0 + 1;
        float wx0 = (1.f - lx) * ((x0 >= 0 && x0 < GW) ? 1.f : 0.f);
        float wx1 = lx         * ((x1 >= 0 && x1 < GW) ? 1.f : 0.f);
        float wy0 = (1.f - ly) * ((y0 >= 0 && y0 < GH) ? 1.f : 0.f);
        float wy1 = ly         * ((y1 >= 0 && y1 < GH) ? 1.f : 0.f);
        int x0c = min(max(x0, 0), GW - 1), x1c = min(max(x1, 0), GW - 1);
        int y0c = min(max(y0, 0), GH - 1), y1c = min(max(y1, 0), GH - 1);
        uint4 r00 = *(const uint4*)(vb + ((size_t)(y0c * GW + x0c) * 512 + sub));
        uint4 r10 = *(const uint4*)(vb + ((size_t)(y0c * GW + x1c) * 512 + sub));
        uint4 r01 = *(const uint4*)(vb + ((size_t)(y1c * GW + x0c) * 512 + sub));
        uint4 r11 = *(const uint4*)(vb + ((size_t)(y1c * GW + x1c) * 512 + sub));
        acc8(acc, wbp * wx0 * wy0, r00);
        acc8(acc, wbp * wx1 * wy0, r10);
        acc8(acc, wbp * wx0 * wy1, r01);
        acc8(acc, wbp * wx1 * wy1, r11);
    }

    #pragma unroll
    for (int i = 0; i < 8; ++i) acc[i] += __shfl_xor(acc[i], 32);

    if (b == 0) {
        uint4 o;
        o.x = pk2(0.5f * acc[0], 0.5f * acc[1]);
        o.y = pk2(0.5f * acc[2], 0.5f * acc[3]);
        o.z = pk2(0.5f * acc[4], 0.5f * acc[5]);
        o.w = pk2(0.5f * acc[6], 0.5f * acc[7]);
        *reinterpret_cast<uint4*>((char*)outm + (size_t)q * 512 + sub) = o;
    }
}

// ---------------------------------------------------------------------------
extern "C" void kernel_launch(void* const* d_in, const int* in_sizes, int n_in,
                              void* d_out, int out_size, void* d_ws, size_t ws_size,
                              hipStream_t stream)
{
    const float* query   = (const float*)d_in[0];
    const float* value   = (const float*)d_in[1];
    const float* rp      = (const float*)d_in[2];
    const float* W_vproj = (const float*)d_in[3];
    const float* b_vproj = (const float*)d_in[4];
    const float* W_so    = (const float*)d_in[5];
    const float* b_so    = (const float*)d_in[6];
    const float* W_aw    = (const float*)d_in[7];
    const float* b_aw    = (const float*)d_in[8];
    const float* W_out   = (const float*)d_in[9];
    const float* b_out   = (const float*)d_in[10];
    float* out = (float*)d_out;

    char* wp = (char*)d_ws;
    unsigned short* ws_v    = (unsigned short*)wp; wp += (size_t)2 * NQ * 256 * 2;
    float*          ws_soaw = (float*)wp;          wp += (size_t)NQ * 192 * 4;
    unsigned short* ws_mean = (unsigned short*)wp; wp += (size_t)NQ * 256 * 2;
    unsigned short* WTv     = (unsigned short*)wp; wp += 256 * 256 * 2;
    unsigned short* WTso    = (unsigned short*)wp; wp += 256 * 512 * 2;
    unsigned short* WTo     = (unsigned short*)wp; wp += 256 * 256 * 2;
    float*          bias2   = (float*)wp;          wp += 256 * 4;

    prep<<<dim3(256), dim3(256), 0, stream>>>(W_vproj, W_so, W_aw, b_so, b_aw, W_out,
                                              WTv, WTso, WTo, bias2);
    gemm_vs<<<dim3(1536), dim3(256), 0, stream>>>(value, query, WTv, WTso,
                                                  b_vproj, bias2, ws_v, ws_soaw);
    sampler<<<dim3(NQ / 4), dim3(256), 0, stream>>>(ws_v, ws_soaw, rp, ws_mean);
    gemm_out<<<dim3(512), dim3(256), 0, stream>>>(ws_mean, WTo, b_out, query, out);
}

// Round 12
// 78.602 us; speedup vs baseline: 6.6720x; 1.1450x over previous
//
#include <hip/hip_runtime.h>
#include <math.h>

#define NQ     16384
#define GW     128
#define GH     128

typedef __attribute__((ext_vector_type(8))) short short8;
typedef __attribute__((ext_vector_type(4))) float f32x4;

static __device__ __forceinline__ unsigned short f2bf(float f) {
    unsigned u = __builtin_bit_cast(unsigned, f);
    u += 0x7FFFu + ((u >> 16) & 1u);          // RNE
    return (unsigned short)(u >> 16);
}
static __device__ __forceinline__ unsigned pk2(float lo, float hi) {
    return (unsigned)f2bf(lo) | ((unsigned)f2bf(hi) << 16);
}
static __device__ __forceinline__ float bflo(unsigned u) {
    return __builtin_bit_cast(float, u << 16);
}
static __device__ __forceinline__ float bfhi(unsigned u) {
    return __builtin_bit_cast(float, u & 0xffff0000u);
}

// ---------------------------------------------------------------------------
// prep: bf16 transposed weights  WT[n][k] = W[k][n]  (+ padded soaw weights)
// ---------------------------------------------------------------------------
__global__ void prep(const float* __restrict__ Wv, const float* __restrict__ Wso,
                     const float* __restrict__ Waw, const float* __restrict__ bso,
                     const float* __restrict__ baw, const float* __restrict__ Wo,
                     unsigned short* __restrict__ WTv, unsigned short* __restrict__ WTso,
                     unsigned short* __restrict__ WTo, float* __restrict__ bias2)
{
    const int n = blockIdx.x;     // 0..255
    const int k = threadIdx.x;    // 0..255
    WTv[n * 256 + k] = f2bf(Wv[(size_t)k * 256 + n]);
    WTo[n * 256 + k] = f2bf(Wo[(size_t)k * 256 + n]);
    float s0, s1;
    if (n < 128)      { s0 = Wso[(size_t)k * 128 + n];       s1 = Wso[(size_t)(k + 256) * 128 + n]; }
    else if (n < 192) { s0 = Waw[(size_t)k * 64 + n - 128];  s1 = Waw[(size_t)(k + 256) * 64 + n - 128]; }
    else              { s0 = 0.f; s1 = 0.f; }
    WTso[(size_t)n * 512 + k]       = f2bf(s0);
    WTso[(size_t)n * 512 + k + 256] = f2bf(s1);
    if (k == 0) bias2[n] = (n < 128) ? bso[n] : ((n < 192) ? baw[n - 128] : 0.f);
}

// ---------------------------------------------------------------------------
// bf16 MFMA GEMM body — round-7 structure (measured best): tile 64x128,
// BK=64, 4 waves (2Mx2N), double-buffered LDS, single barrier per k-step,
// next-tile global loads issued before compute. 16B-chunk XOR bank swizzle
// (without it: 16-way read conflict; with it: 2-lanes/bank floor).
// MODE 0: vproj  (A=fp32 A1, out bf16 ldc256, +bias)
// MODE 1: soaw   (A=concat(A1,A2) fp32, out fp32 ldc192 col<192, +bias)
// MODE 2: outproj(A=bf16 Abf,  out fp32 ldc256, +bias +resid)
// LDS: As 2x[64][64] bf16 (8KB each), Bs 2x[128][64] bf16 (16KB each) = 48KB
// ---------------------------------------------------------------------------
template<int KTOT, int MODE>
static __device__ __forceinline__ void gemm_body(
    int m0, int n0,
    const float* __restrict__ A1, const float* __restrict__ A2,
    const unsigned short* __restrict__ Abf,
    const unsigned short* __restrict__ WT,
    const float* __restrict__ bias, const float* __restrict__ resid,
    void* __restrict__ Cout,
    unsigned short* As, unsigned short* Bs)
{
    const int tid = threadIdx.x;
    const int w = tid >> 6, lane = tid & 63;
    const int wr = w >> 1, wc = w & 1;
    const int g = lane >> 4, r16 = lane & 15;
    const int arow = tid >> 3, aoc = tid & 7;   // staging coords
    const int NT = KTOT / 64;

    float4 ra[4];     // fp32 A staging: 2 rows x 2 float4
    uint4  rab[2];    // bf16 A staging
    uint4  rb[4];     // B staging: 4 rows x 1 uint4
    f32x4 acc[2][4] = {};

#define LOAD_T(t)                                                               \
    {                                                                           \
        int k0 = (t) * 64;                                                      \
        if (MODE == 2) {                                                        \
            _Pragma("unroll")                                                   \
            for (int i = 0; i < 2; ++i)                                         \
                rab[i] = *(const uint4*)&Abf[(size_t)(m0 + arow + i * 32) * 256 \
                                             + k0 + aoc * 8];                   \
        } else {                                                                \
            const float* Asrc = (KTOT == 512 && k0 >= 256) ? (A2 + (k0 - 256))  \
                                                           : (A1 + k0);         \
            _Pragma("unroll")                                                   \
            for (int i = 0; i < 2; ++i) {                                       \
                const float* p = Asrc + (size_t)(m0 + arow + i * 32) * 256      \
                                 + aoc * 8;                                     \
                ra[i * 2 + 0] = *(const float4*)p;                              \
                ra[i * 2 + 1] = *(const float4*)(p + 4);                        \
            }                                                                   \
        }                                                                       \
        _Pragma("unroll")                                                       \
        for (int i = 0; i < 4; ++i)                                             \
            rb[i] = *(const uint4*)&WT[(size_t)(n0 + arow + i * 32) * KTOT      \
                                       + k0 + aoc * 8];                         \
    }

#define SWZ(row, chunk) (((chunk) ^ ((row) & 7)) * 8)

#define WRITE_T(bufi)                                                           \
    {                                                                           \
        unsigned short* Ab = As + (bufi) * 64 * 64;                             \
        unsigned short* Bb = Bs + (bufi) * 128 * 64;                            \
        if (MODE == 2) {                                                        \
            _Pragma("unroll")                                                   \
            for (int i = 0; i < 2; ++i) {                                       \
                int r = arow + i * 32;                                          \
                *(uint4*)&Ab[r * 64 + SWZ(r, aoc)] = rab[i];                    \
            }                                                                   \
        } else {                                                                \
            _Pragma("unroll")                                                   \
            for (int i = 0; i < 2; ++i) {                                       \
                uint4 wv;                                                       \
                wv.x = pk2(ra[i * 2].x, ra[i * 2].y);                           \
                wv.y = pk2(ra[i * 2].z, ra[i * 2].w);                           \
                wv.z = pk2(ra[i * 2 + 1].x, ra[i * 2 + 1].y);                   \
                wv.w = pk2(ra[i * 2 + 1].z, ra[i * 2 + 1].w);                   \
                int r = arow + i * 32;                                          \
                *(uint4*)&Ab[r * 64 + SWZ(r, aoc)] = wv;                        \
            }                                                                   \
        }                                                                       \
        _Pragma("unroll")                                                       \
        for (int i = 0; i < 4; ++i) {                                           \
            int r = arow + i * 32;                                              \
            *(uint4*)&Bb[r * 64 + SWZ(r, aoc)] = rb[i];                         \
        }                                                                       \
    }

    LOAD_T(0);
    WRITE_T(0);
    __syncthreads();

    for (int t = 0; t < NT; ++t) {
        if (t + 1 < NT) LOAD_T(t + 1);       // issue next tile's global loads
        const unsigned short* Ab = As + (t & 1) * 64 * 64;
        const unsigned short* Bb = Bs + (t & 1) * 128 * 64;
        #pragma unroll
        for (int kh = 0; kh < 2; ++kh) {
            short8 af[2], bfr[4];
            #pragma unroll
            for (int mi = 0; mi < 2; ++mi) {
                int r = wr * 32 + mi * 16 + r16;
                af[mi] = *(const short8*)&Ab[r * 64 + SWZ(r, kh * 4 + g)];
            }
            #pragma unroll
            for (int nj = 0; nj < 4; ++nj) {
                int r = wc * 64 + nj * 16 + r16;
                bfr[nj] = *(const short8*)&Bb[r * 64 + SWZ(r, kh * 4 + g)];
            }
            #pragma unroll
            for (int mi = 0; mi < 2; ++mi)
                #pragma unroll
                for (int nj = 0; nj < 4; ++nj)
                    acc[mi][nj] = __builtin_amdgcn_mfma_f32_16x16x32_bf16(
                        af[mi], bfr[nj], acc[mi][nj], 0, 0, 0);
        }
        if (t + 1 < NT) WRITE_T((t + 1) & 1);  // lands in the other buffer
        __syncthreads();
    }
#undef LOAD_T
#undef WRITE_T
#undef SWZ

    #pragma unroll
    for (int mi = 0; mi < 2; ++mi) {
        int row = m0 + wr * 32 + mi * 16 + g * 4;
        #pragma unroll
        for (int nj = 0; nj < 4; ++nj) {
            int col = n0 + wc * 64 + nj * 16 + r16;
            if (MODE == 1 && col >= 192) continue;
            float bia = bias[col];
            #pragma unroll
            for (int j = 0; j < 4; ++j) {
                float vo = acc[mi][nj][j] + bia;
                if (MODE == 0) {
                    ((unsigned short*)Cout)[(size_t)(row + j) * 256 + col] = f2bf(vo);
                } else if (MODE == 1) {
                    ((float*)Cout)[(size_t)(row + j) * 192 + col] = vo;
                } else {
                    ((float*)Cout)[(size_t)(row + j) * 256 + col] =
                        vo + resid[(size_t)(row + j) * 256 + col];
                }
            }
        }
    }
}

// ---------------------------------------------------------------------------
// vproj + soaw merged. ORDER MATTERS: soaw roles (K=512, 8 k-steps, 2x work)
// occupy bids 0..511 so the LONG blocks dispatch FIRST; the short 4-step
// vproj blocks (bids 512..1535) drain behind them. With vproj first (r7),
// the 512 long soaw blocks formed the final dispatch wave at ~2-3 blocks/CU
// — a serial tail. This inverts it.
// ---------------------------------------------------------------------------
__global__ __launch_bounds__(256)
void gemm_vs(const float* __restrict__ value, const float* __restrict__ query,
             const unsigned short* __restrict__ WTv, const unsigned short* __restrict__ WTso,
             const float* __restrict__ bv, const float* __restrict__ bias2,
             unsigned short* __restrict__ v_out, float* __restrict__ soaw_out)
{
    __shared__ __align__(16) unsigned short As[2 * 64 * 64];
    __shared__ __align__(16) unsigned short Bs[2 * 128 * 64];
    const int bid = blockIdx.x;
    if (bid < 512) {
        gemm_body<512, 1>((bid >> 1) * 64, (bid & 1) * 128,
                          value, query, nullptr, WTso, bias2, nullptr, soaw_out, As, Bs);
    } else {
        const int b2 = bid - 512;
        gemm_body<256, 0>((b2 >> 1) * 64, (b2 & 1) * 128,
                          value, nullptr, nullptr, WTv, bv, nullptr, v_out, As, Bs);
    }
}

__global__ __launch_bounds__(256)
void gemm_out(const unsigned short* __restrict__ Abf, const unsigned short* __restrict__ WTo,
              const float* __restrict__ bo, const float* __restrict__ resid,
              float* __restrict__ out)
{
    __shared__ __align__(16) unsigned short As[2 * 64 * 64];
    __shared__ __align__(16) unsigned short Bs[2 * 128 * 64];
    gemm_body<256, 2>((blockIdx.x >> 1) * 64, (blockIdx.x & 1) * 128,
                      nullptr, nullptr, Abf, WTo, bo, resid, out, As, Bs);
}

// ---------------------------------------------------------------------------
// Sampler v4 (round-7, unchanged): one WAVE per q. lane ln: b=ln>>5,
// h=(ln>>2)&7, c=ln&3. 16 uint4 gathers/lane; halves via __shfl_xor(32).
// 4096 blocks (4 q each), XCD-aware band swizzle (band fits 4MB L2).
// ---------------------------------------------------------------------------
static __device__ __forceinline__ void acc8(float* acc, float w, uint4 r) {
    acc[0] = fmaf(w, bflo(r.x), acc[0]);
    acc[1] = fmaf(w, bfhi(r.x), acc[1]);
    acc[2] = fmaf(w, bflo(r.y), acc[2]);
    acc[3] = fmaf(w, bfhi(r.y), acc[3]);
    acc[4] = fmaf(w, bflo(r.z), acc[4]);
    acc[5] = fmaf(w, bfhi(r.z), acc[5]);
    acc[6] = fmaf(w, bflo(r.w), acc[6]);
    acc[7] = fmaf(w, bfhi(r.w), acc[7]);
}

__global__ __launch_bounds__(256)
void sampler(const unsigned short* __restrict__ v, const float* __restrict__ soaw,
             const float* __restrict__ rp, unsigned short* __restrict__ outm)
{
    __shared__ float so_s[4][128];
    __shared__ float w_s[4][64];
    __shared__ float rp_s[4][2];

    const int t = threadIdx.x;
    const int bid = blockIdx.x;
    const int q0 = ((bid & 7) * 512 + (bid >> 3)) * 4;

    #pragma unroll
    for (int i = 0; i < 2; ++i) {
        int idx = t + i * 256;
        int qq = idx >> 7, off = idx & 127;
        so_s[qq][off] = soaw[(size_t)(q0 + qq) * 192 + off];
    }
    if (t < 64) {             // in-lane softmax: one lane per (q, h, b)
        int qq = t >> 4, grp = t & 15;
        float4 a4 = *reinterpret_cast<const float4*>(
            &soaw[(size_t)(q0 + qq) * 192 + 128 + grp * 4]);
        float m = fmaxf(fmaxf(a4.x, a4.y), fmaxf(a4.z, a4.w));
        float e0 = __expf(a4.x - m), e1 = __expf(a4.y - m);
        float e2 = __expf(a4.z - m), e3 = __expf(a4.w - m);
        float inv = 1.f / (e0 + e1 + e2 + e3);
        w_s[qq][grp * 4 + 0] = e0 * inv;
        w_s[qq][grp * 4 + 1] = e1 * inv;
        w_s[qq][grp * 4 + 2] = e2 * inv;
        w_s[qq][grp * 4 + 3] = e3 * inv;
    }
    if (t < 8) rp_s[t >> 1][t & 1] = rp[(size_t)(q0 + (t >> 1)) * 2 + (t & 1)];
    __syncthreads();

    const int wq = t >> 6;                 // block-local q (0..3), one wave each
    const int q = q0 + wq;
    const int ln = t & 63;
    const int b = ln >> 5;                 // temporal half on lanes
    const int s = ln & 31;
    const int h = s >> 2, c = s & 3;
    const int sub = h * 64 + c * 16;       // byte offset inside a 512B v row
    const float rpx = rp_s[wq][0], rpy = rp_s[wq][1];
    const char* vb = (const char*)v + (size_t)b * NQ * 512;
    float acc[8] = {};

    #pragma unroll
    for (int p = 0; p < 4; ++p) {
        float sox = so_s[wq][h * 16 + b * 8 + p * 2 + 0];
        float soy = so_s[wq][h * 16 + b * 8 + p * 2 + 1];
        float wbp = w_s[wq][h * 8 + b * 4 + p];
        float px = (rpx + sox * (1.0f / 128.0f)) * 128.0f - 0.5f;
        float py = (rpy + soy * (1.0f / 128.0f)) * 128.0f - 0.5f;
        float x0f = floorf(px), y0f = floorf(py);
        float lx = px - x0f, ly = py - y0f;
        int x0 = (int)x0f, y0 = (int)y0f;
        int x1 = x0 + 1, y1 = y0 + 1;
        float wx0 = (1.f - lx) * ((x0 >= 0 && x0 < GW) ? 1.f : 0.f);
        float wx1 = lx         * ((x1 >= 0 && x1 < GW) ? 1.f : 0.f);
        float wy0 = (1.f - ly) * ((y0 >= 0 && y0 < GH) ? 1.f : 0.f);
        float wy1 = ly         * ((y1 >= 0 && y1 < GH) ? 1.f : 0.f);
        int x0c = min(max(x0, 0), GW - 1), x1c = min(max(x1, 0), GW - 1);
        int y0c = min(max(y0, 0), GH - 1), y1c = min(max(y1, 0), GH - 1);
        uint4 r00 = *(const uint4*)(vb + ((size_t)(y0c * GW + x0c) * 512 + sub));
        uint4 r10 = *(const uint4*)(vb + ((size_t)(y0c * GW + x1c) * 512 + sub));
        uint4 r01 = *(const uint4*)(vb + ((size_t)(y1c * GW + x0c) * 512 + sub));
        uint4 r11 = *(const uint4*)(vb + ((size_t)(y1c * GW + x1c) * 512 + sub));
        acc8(acc, wbp * wx0 * wy0, r00);
        acc8(acc, wbp * wx1 * wy0, r10);
        acc8(acc, wbp * wx0 * wy1, r01);
        acc8(acc, wbp * wx1 * wy1, r11);
    }

    #pragma unroll
    for (int i = 0; i < 8; ++i) acc[i] += __shfl_xor(acc[i], 32);

    if (b == 0) {
        uint4 o;
        o.x = pk2(0.5f * acc[0], 0.5f * acc[1]);
        o.y = pk2(0.5f * acc[2], 0.5f * acc[3]);
        o.z = pk2(0.5f * acc[4], 0.5f * acc[5]);
        o.w = pk2(0.5f * acc[6], 0.5f * acc[7]);
        *reinterpret_cast<uint4*>((char*)outm + (size_t)q * 512 + sub) = o;
    }
}

// ---------------------------------------------------------------------------
extern "C" void kernel_launch(void* const* d_in, const int* in_sizes, int n_in,
                              void* d_out, int out_size, void* d_ws, size_t ws_size,
                              hipStream_t stream)
{
    const float* query   = (const float*)d_in[0];
    const float* value   = (const float*)d_in[1];
    const float* rp      = (const float*)d_in[2];
    const float* W_vproj = (const float*)d_in[3];
    const float* b_vproj = (const float*)d_in[4];
    const float* W_so    = (const float*)d_in[5];
    const float* b_so    = (const float*)d_in[6];
    const float* W_aw    = (const float*)d_in[7];
    const float* b_aw    = (const float*)d_in[8];
    const float* W_out   = (const float*)d_in[9];
    const float* b_out   = (const float*)d_in[10];
    float* out = (float*)d_out;

    char* wp = (char*)d_ws;
    unsigned short* ws_v    = (unsigned short*)wp; wp += (size_t)2 * NQ * 256 * 2;
    float*          ws_soaw = (float*)wp;          wp += (size_t)NQ * 192 * 4;
    unsigned short* ws_mean = (unsigned short*)wp; wp += (size_t)NQ * 256 * 2;
    unsigned short* WTv     = (unsigned short*)wp; wp += 256 * 256 * 2;
    unsigned short* WTso    = (unsigned short*)wp; wp += 256 * 512 * 2;
    unsigned short* WTo     = (unsigned short*)wp; wp += 256 * 256 * 2;
    float*          bias2   = (float*)wp;          wp += 256 * 4;

    prep<<<dim3(256), dim3(256), 0, stream>>>(W_vproj, W_so, W_aw, b_so, b_aw, W_out,
                                              WTv, WTso, WTo, bias2);
    gemm_vs<<<dim3(1536), dim3(256), 0, stream>>>(value, query, WTv, WTso,
                                                  b_vproj, bias2, ws_v, ws_soaw);
    sampler<<<dim3(NQ / 4), dim3(256), 0, stream>>>(ws_v, ws_soaw, rp, ws_mean);
    gemm_out<<<dim3(512), dim3(256), 0, stream>>>(ws_mean, WTo, b_out, query, out);
}